// Round 1
// baseline (698.682 us; speedup 1.0000x reference)
//
#include <hip/hip_runtime.h>
#include <hip/hip_bf16.h>

typedef unsigned short u16;
typedef unsigned int   u32;

static constexpr int Bc = 8, Ac = 64, Tc = 128, Cc = 256, Hc = 8;
static constexpr int NROW = Bc * Ac * Tc;   // 65536 tokens
static constexpr int DH = Cc / Hc;          // 32

__device__ __forceinline__ float bf2f(u16 h) {
    u32 u = ((u32)h) << 16; float f; __builtin_memcpy(&f, &u, 4); return f;
}
__device__ __forceinline__ u16 f2bf(float f) {
    u32 u; __builtin_memcpy(&u, &f, 4);
    u += 0x7fffu + ((u >> 16) & 1u);   // RNE
    return (u16)(u >> 16);
}

typedef __attribute__((ext_vector_type(8))) short  short8v;
typedef __attribute__((ext_vector_type(4))) float  float4v;

// ---------------- cast fp32 -> bf16 (weights) ----------------
__global__ void cast_kernel(const float* __restrict__ in, u16* __restrict__ out, int n) {
    int i = blockIdx.x * 256 + threadIdx.x;
    if (i < n) out[i] = f2bf(in[i]);
}

// ---------------- LayerNorm, fp32 input -> bf16 out ----------------
__global__ __launch_bounds__(256) void ln_f32(const float* __restrict__ in,
        const float* __restrict__ w, const float* __restrict__ b,
        u16* __restrict__ out) {
    int row  = blockIdx.x * 4 + (threadIdx.x >> 6);
    int lane = threadIdx.x & 63;
    const float* rp = in + (size_t)row * Cc + lane * 4;
    float4 v = *(const float4*)rp;
    float s  = v.x + v.y + v.z + v.w;
    float sq = v.x * v.x + v.y * v.y + v.z * v.z + v.w * v.w;
    for (int off = 32; off; off >>= 1) { s += __shfl_xor(s, off); sq += __shfl_xor(sq, off); }
    float mean = s * (1.f / Cc);
    float rs = rsqrtf(sq * (1.f / Cc) - mean * mean + 1e-5f);
    int c0 = lane * 4;
    float vv[4] = {v.x, v.y, v.z, v.w};
    ushort4 ov;
    ov.x = f2bf((vv[0] - mean) * rs * w[c0 + 0] + b[c0 + 0]);
    ov.y = f2bf((vv[1] - mean) * rs * w[c0 + 1] + b[c0 + 1]);
    ov.z = f2bf((vv[2] - mean) * rs * w[c0 + 2] + b[c0 + 2]);
    ov.w = f2bf((vv[3] - mean) * rs * w[c0 + 3] + b[c0 + 3]);
    *(ushort4*)(out + (size_t)row * Cc + c0) = ov;
}

// ---------------- LayerNorm, bf16 input -> bf16 out ----------------
__global__ __launch_bounds__(256) void ln_bf16(const u16* __restrict__ in,
        const float* __restrict__ w, const float* __restrict__ b,
        u16* __restrict__ out) {
    int row  = blockIdx.x * 4 + (threadIdx.x >> 6);
    int lane = threadIdx.x & 63;
    const u16* rp = in + (size_t)row * Cc + lane * 4;
    ushort4 hv = *(const ushort4*)rp;
    float vv[4] = {bf2f(hv.x), bf2f(hv.y), bf2f(hv.z), bf2f(hv.w)};
    float s = vv[0] + vv[1] + vv[2] + vv[3];
    float sq = vv[0]*vv[0] + vv[1]*vv[1] + vv[2]*vv[2] + vv[3]*vv[3];
    for (int off = 32; off; off >>= 1) { s += __shfl_xor(s, off); sq += __shfl_xor(sq, off); }
    float mean = s * (1.f / Cc);
    float rs = rsqrtf(sq * (1.f / Cc) - mean * mean + 1e-5f);
    int c0 = lane * 4;
    ushort4 ov;
    ov.x = f2bf((vv[0] - mean) * rs * w[c0 + 0] + b[c0 + 0]);
    ov.y = f2bf((vv[1] - mean) * rs * w[c0 + 1] + b[c0 + 1]);
    ov.z = f2bf((vv[2] - mean) * rs * w[c0 + 2] + b[c0 + 2]);
    ov.w = f2bf((vv[3] - mean) * rs * w[c0 + 3] + b[c0 + 3]);
    *(ushort4*)(out + (size_t)row * Cc + c0) = ov;
}

// ---------------- GEMM: out[M][N] = X[M][K] @ W[N][K]^T + bias ----------------
// EPI: 0 = bias, store bf16
//      1 = bias + residual(res) -> store bf16        (proj -> x2)
//      2 = bias + exact GELU -> store bf16           (fc1 -> h)
//      3 = bias + residual(res) -> store fp32 to outf (fc2 -> d_out)
template<int K, int EPI>
__global__ __launch_bounds__(256) void gemm_bt(
        const u16* __restrict__ X, const u16* __restrict__ W,
        const float* __restrict__ bias,
        u16* __restrict__ outb, float* __restrict__ outf,
        const u16* __restrict__ res, int Nfeat) {
    __shared__ u16 lx[4][64][8];   // [kchunk][row][8]  fragment-order
    __shared__ u16 lw[4][64][8];
    const int bm = blockIdx.x * 64, bn = blockIdx.y * 64;
    const int tid = threadIdx.x;
    const int lane = tid & 63;
    const int wm = ((tid >> 6) >> 1) * 32, wn = ((tid >> 6) & 1) * 32;
    const int srow = tid >> 2, skc = tid & 3;
    const u16* xp = X + (size_t)(bm + srow) * K + skc * 8;
    const u16* wp = W + (size_t)(bn + srow) * K + skc * 8;
    float4v acc[2][2] = {};
    for (int k0 = 0; k0 < K; k0 += 32) {
        *(uint4*)(&lx[skc][srow][0]) = *(const uint4*)(xp + k0);
        *(uint4*)(&lw[skc][srow][0]) = *(const uint4*)(wp + k0);
        __syncthreads();
        const int lk = lane >> 4, lr = lane & 15;
        short8v a0 = *(const short8v*)(&lx[lk][wm + lr][0]);
        short8v a1 = *(const short8v*)(&lx[lk][wm + 16 + lr][0]);
        short8v b0 = *(const short8v*)(&lw[lk][wn + lr][0]);
        short8v b1 = *(const short8v*)(&lw[lk][wn + 16 + lr][0]);
        acc[0][0] = __builtin_amdgcn_mfma_f32_16x16x32_bf16(a0, b0, acc[0][0], 0, 0, 0);
        acc[0][1] = __builtin_amdgcn_mfma_f32_16x16x32_bf16(a0, b1, acc[0][1], 0, 0, 0);
        acc[1][0] = __builtin_amdgcn_mfma_f32_16x16x32_bf16(a1, b0, acc[1][0], 0, 0, 0);
        acc[1][1] = __builtin_amdgcn_mfma_f32_16x16x32_bf16(a1, b1, acc[1][1], 0, 0, 0);
        __syncthreads();
    }
    // C/D layout (verified m89): col = lane&15, row = (lane>>4)*4 + reg
    const int rr = (lane >> 4) * 4, cc0 = lane & 15;
    for (int i = 0; i < 2; i++)
        for (int j = 0; j < 2; j++) {
            int c = bn + wn + j * 16 + cc0;
            float bv = bias[c];
            for (int r4 = 0; r4 < 4; r4++) {
                int r = bm + wm + i * 16 + rr + r4;
                float v = acc[i][j][r4] + bv;
                size_t oidx = (size_t)r * Nfeat + c;
                if (EPI == 1) v += bf2f(res[oidx]);
                if (EPI == 2) v = 0.5f * v * (1.f + erff(v * 0.70710678118654752f));
                if (EPI == 3) {
                    outf[oidx] = v + bf2f(res[oidx]);
                } else {
                    outb[oidx] = f2bf(v);
                }
            }
        }
}

// ---------------- attention: one block per (b,a,h), 128 threads ----------------
__global__ __launch_bounds__(128) void attn_kernel(
        const u16* __restrict__ qkv, const unsigned char* __restrict__ mask,
        u16* __restrict__ out) {
    __shared__ u16 sk[128][32];
    __shared__ u16 sv[128][32];
    __shared__ u16 ss[128][134];   // scores row per thread, padded (2-way banks only)
    const int blk = blockIdx.x;
    const int h = blk & (Hc - 1);
    const int ba = blk >> 3;
    const size_t rowbase = (size_t)ba * Tc;
    const int t = threadIdx.x;
    const u16* base = qkv + (rowbase + t) * (3 * Cc);
    const u16* kp = base + Cc + h * DH;
    const u16* vp = base + 2 * Cc + h * DH;
    #pragma unroll
    for (int i = 0; i < 4; i++) {
        ((uint4*)&sk[t][0])[i] = ((const uint4*)kp)[i];
        ((uint4*)&sv[t][0])[i] = ((const uint4*)vp)[i];
    }
    float qf[DH];
    const u16* qp = base + h * DH;
    #pragma unroll
    for (int i = 0; i < DH; i++) qf[i] = bf2f(qp[i]) * 0.17677669529663687f; // 1/sqrt(32)
    __syncthreads();
    for (int s = 0; s < Tc; s++) {
        float a = 0.f;
        #pragma unroll
        for (int d = 0; d < DH; d++) a += qf[d] * bf2f(sk[s][d]);
        ss[t][s] = f2bf(a);
    }
    float m = -1e30f;
    for (int s = 0; s < Tc; s++) m = fmaxf(m, bf2f(ss[t][s]));
    float sum = 0.f;
    for (int s = 0; s < Tc; s++) {
        float e = __expf(bf2f(ss[t][s]) - m);
        sum += e;
        ss[t][s] = f2bf(e);
    }
    const bool msk = mask[rowbase + t] != 0;
    const float inv = 1.f / sum;
    const float pu = 1.f / Tc;    // masked rows: softmax of all-equal = uniform
    float acc[DH];
    #pragma unroll
    for (int d = 0; d < DH; d++) acc[d] = 0.f;
    for (int s = 0; s < Tc; s++) {
        float p = msk ? pu : bf2f(ss[t][s]) * inv;
        #pragma unroll
        for (int d = 0; d < DH; d++) acc[d] += p * bf2f(sv[s][d]);
    }
    u16* op = out + (rowbase + t) * Cc + h * DH;
    #pragma unroll
    for (int d = 0; d < DH; d++) op[d] = f2bf(acc[d]);
}

extern "C" void kernel_launch(void* const* d_in, const int* in_sizes, int n_in,
                              void* d_out, int out_size, void* d_ws, size_t ws_size,
                              hipStream_t stream) {
    const float* x      = (const float*)d_in[0];
    const unsigned char* mask = (const unsigned char*)d_in[1];
    const float* ln1_w  = (const float*)d_in[2];
    const float* ln1_b  = (const float*)d_in[3];
    const float* qkv_w  = (const float*)d_in[4];
    const float* qkv_b  = (const float*)d_in[5];
    const float* proj_w = (const float*)d_in[6];
    const float* proj_b = (const float*)d_in[7];
    const float* ln2_w  = (const float*)d_in[8];
    const float* ln2_b  = (const float*)d_in[9];
    const float* fc1_w  = (const float*)d_in[10];
    const float* fc1_b  = (const float*)d_in[11];
    const float* fc2_w  = (const float*)d_in[12];
    const float* fc2_b  = (const float*)d_in[13];
    float* out = (float*)d_out;

    char* ws = (char*)d_ws;
    size_t off = 0;
    auto alloc = [&](size_t elems) -> u16* {
        u16* p = (u16*)(ws + off);
        off += ((elems * 2 + 255) / 256) * 256;
        return p;
    };
    u16* wqb  = alloc(768 * 256);
    u16* wpb  = alloc(256 * 256);
    u16* w1b  = alloc(1024 * 256);
    u16* w2b  = alloc(256 * 1024);
    u16* x1b  = alloc((size_t)NROW * Cc);        // x1 bf16; region reused for x3 later
    u16* qkvb = alloc((size_t)NROW * 3 * Cc);    // qkv; region reused for h later
    u16* attb = alloc((size_t)NROW * Cc);        // attn out (contiguous after qkv)
    u16* x2b  = alloc((size_t)NROW * Cc);
    u16* hb   = qkvb;   // fc1 output: 4*N*C elems == qkv(3NC)+attn(NC), both dead by then
    u16* x3b  = x1b;    // x1 dead after proj epilogue; ln2 runs after proj

    // 1) weights -> bf16
    cast_kernel<<<(196608 + 255) / 256, 256, 0, stream>>>(qkv_w, wqb, 196608);
    cast_kernel<<<(65536  + 255) / 256, 256, 0, stream>>>(proj_w, wpb, 65536);
    cast_kernel<<<(262144 + 255) / 256, 256, 0, stream>>>(fc1_w, w1b, 262144);
    cast_kernel<<<(262144 + 255) / 256, 256, 0, stream>>>(fc2_w, w2b, 262144);
    // 2) x1 = LN1(x)
    ln_f32<<<NROW / 4, 256, 0, stream>>>(x, ln1_w, ln1_b, x1b);
    // 3) qkv = x1 @ qkv_w^T + b
    gemm_bt<256, 0><<<dim3(NROW / 64, 768 / 64), 256, 0, stream>>>(
        x1b, wqb, qkv_b, qkvb, nullptr, nullptr, 768);
    // 4) attention per (b,a,h)
    attn_kernel<<<Bc * Ac * Hc, 128, 0, stream>>>(qkvb, mask, attb);
    // 5) x2 = x1 + attn @ proj_w^T + b
    gemm_bt<256, 1><<<dim3(NROW / 64, 256 / 64), 256, 0, stream>>>(
        attb, wpb, proj_b, x2b, nullptr, x1b, 256);
    // 6) x3 = LN2(x2)
    ln_bf16<<<NROW / 4, 256, 0, stream>>>(x2b, ln2_w, ln2_b, x3b);
    // 7) h = gelu(x3 @ fc1_w^T + b)
    gemm_bt<256, 2><<<dim3(NROW / 64, 1024 / 64), 256, 0, stream>>>(
        x3b, w1b, fc1_b, hb, nullptr, nullptr, 1024);
    // 8) out = x3 + h @ fc2_w^T + b   (fp32)
    gemm_bt<1024, 3><<<dim3(NROW / 64, 256 / 64), 256, 0, stream>>>(
        hb, w2b, fc2_b, nullptr, out, x3b, 256);
}

// Round 2
// 434.354 us; speedup vs baseline: 1.6086x; 1.6086x over previous
//
#include <hip/hip_runtime.h>
#include <hip/hip_bf16.h>

typedef unsigned short u16;
typedef unsigned int   u32;

static constexpr int Bc = 8, Ac = 64, Tc = 128, Cc = 256, Hc = 8;
static constexpr int NROW = Bc * Ac * Tc;   // 65536 tokens
static constexpr int DH = Cc / Hc;          // 32

__device__ __forceinline__ float bf2f(u16 h) {
    u32 u = ((u32)h) << 16; float f; __builtin_memcpy(&f, &u, 4); return f;
}
__device__ __forceinline__ u16 f2bf(float f) {
    u32 u; __builtin_memcpy(&u, &f, 4);
    u += 0x7fffu + ((u >> 16) & 1u);   // RNE
    return (u16)(u >> 16);
}

typedef __attribute__((ext_vector_type(8))) short  short8v;
typedef __attribute__((ext_vector_type(4))) float  float4v;

// ---------------- cast fp32 -> bf16 (weights) ----------------
__global__ void cast_kernel(const float* __restrict__ in, u16* __restrict__ out, int n) {
    int i = blockIdx.x * 256 + threadIdx.x;
    if (i < n) out[i] = f2bf(in[i]);
}

// ---------------- LayerNorm, fp32 input -> bf16 out ----------------
__global__ __launch_bounds__(256) void ln_f32(const float* __restrict__ in,
        const float* __restrict__ w, const float* __restrict__ b,
        u16* __restrict__ out) {
    int row  = blockIdx.x * 4 + (threadIdx.x >> 6);
    int lane = threadIdx.x & 63;
    const float* rp = in + (size_t)row * Cc + lane * 4;
    float4 v = *(const float4*)rp;
    float s  = v.x + v.y + v.z + v.w;
    float sq = v.x * v.x + v.y * v.y + v.z * v.z + v.w * v.w;
    for (int off = 32; off; off >>= 1) { s += __shfl_xor(s, off); sq += __shfl_xor(sq, off); }
    float mean = s * (1.f / Cc);
    float rs = rsqrtf(sq * (1.f / Cc) - mean * mean + 1e-5f);
    int c0 = lane * 4;
    float vv[4] = {v.x, v.y, v.z, v.w};
    ushort4 ov;
    ov.x = f2bf((vv[0] - mean) * rs * w[c0 + 0] + b[c0 + 0]);
    ov.y = f2bf((vv[1] - mean) * rs * w[c0 + 1] + b[c0 + 1]);
    ov.z = f2bf((vv[2] - mean) * rs * w[c0 + 2] + b[c0 + 2]);
    ov.w = f2bf((vv[3] - mean) * rs * w[c0 + 3] + b[c0 + 3]);
    *(ushort4*)(out + (size_t)row * Cc + c0) = ov;
}

// ---------------- LayerNorm, bf16 input -> bf16 out ----------------
__global__ __launch_bounds__(256) void ln_bf16(const u16* __restrict__ in,
        const float* __restrict__ w, const float* __restrict__ b,
        u16* __restrict__ out) {
    int row  = blockIdx.x * 4 + (threadIdx.x >> 6);
    int lane = threadIdx.x & 63;
    const u16* rp = in + (size_t)row * Cc + lane * 4;
    ushort4 hv = *(const ushort4*)rp;
    float vv[4] = {bf2f(hv.x), bf2f(hv.y), bf2f(hv.z), bf2f(hv.w)};
    float s = vv[0] + vv[1] + vv[2] + vv[3];
    float sq = vv[0]*vv[0] + vv[1]*vv[1] + vv[2]*vv[2] + vv[3]*vv[3];
    for (int off = 32; off; off >>= 1) { s += __shfl_xor(s, off); sq += __shfl_xor(sq, off); }
    float mean = s * (1.f / Cc);
    float rs = rsqrtf(sq * (1.f / Cc) - mean * mean + 1e-5f);
    int c0 = lane * 4;
    ushort4 ov;
    ov.x = f2bf((vv[0] - mean) * rs * w[c0 + 0] + b[c0 + 0]);
    ov.y = f2bf((vv[1] - mean) * rs * w[c0 + 1] + b[c0 + 1]);
    ov.z = f2bf((vv[2] - mean) * rs * w[c0 + 2] + b[c0 + 2]);
    ov.w = f2bf((vv[3] - mean) * rs * w[c0 + 3] + b[c0 + 3]);
    *(ushort4*)(out + (size_t)row * Cc + c0) = ov;
}

// ---------------- GEMM: out[M][N] = X[M][K] @ W[N][K]^T + bias ----------------
template<int K, int EPI>
__global__ __launch_bounds__(256) void gemm_bt(
        const u16* __restrict__ X, const u16* __restrict__ W,
        const float* __restrict__ bias,
        u16* __restrict__ outb, float* __restrict__ outf,
        const u16* __restrict__ res, int Nfeat) {
    __shared__ u16 lx[4][64][8];   // [kchunk][row][8]  fragment-order
    __shared__ u16 lw[4][64][8];
    const int bm = blockIdx.x * 64, bn = blockIdx.y * 64;
    const int tid = threadIdx.x;
    const int lane = tid & 63;
    const int wm = ((tid >> 6) >> 1) * 32, wn = ((tid >> 6) & 1) * 32;
    const int srow = tid >> 2, skc = tid & 3;
    const u16* xp = X + (size_t)(bm + srow) * K + skc * 8;
    const u16* wp = W + (size_t)(bn + srow) * K + skc * 8;
    float4v acc[2][2] = {};
    for (int k0 = 0; k0 < K; k0 += 32) {
        *(uint4*)(&lx[skc][srow][0]) = *(const uint4*)(xp + k0);
        *(uint4*)(&lw[skc][srow][0]) = *(const uint4*)(wp + k0);
        __syncthreads();
        const int lk = lane >> 4, lr = lane & 15;
        short8v a0 = *(const short8v*)(&lx[lk][wm + lr][0]);
        short8v a1 = *(const short8v*)(&lx[lk][wm + 16 + lr][0]);
        short8v b0 = *(const short8v*)(&lw[lk][wn + lr][0]);
        short8v b1 = *(const short8v*)(&lw[lk][wn + 16 + lr][0]);
        acc[0][0] = __builtin_amdgcn_mfma_f32_16x16x32_bf16(a0, b0, acc[0][0], 0, 0, 0);
        acc[0][1] = __builtin_amdgcn_mfma_f32_16x16x32_bf16(a0, b1, acc[0][1], 0, 0, 0);
        acc[1][0] = __builtin_amdgcn_mfma_f32_16x16x32_bf16(a1, b0, acc[1][0], 0, 0, 0);
        acc[1][1] = __builtin_amdgcn_mfma_f32_16x16x32_bf16(a1, b1, acc[1][1], 0, 0, 0);
        __syncthreads();
    }
    const int rr = (lane >> 4) * 4, cc0 = lane & 15;
    for (int i = 0; i < 2; i++)
        for (int j = 0; j < 2; j++) {
            int c = bn + wn + j * 16 + cc0;
            float bv = bias[c];
            for (int r4 = 0; r4 < 4; r4++) {
                int r = bm + wm + i * 16 + rr + r4;
                float v = acc[i][j][r4] + bv;
                size_t oidx = (size_t)r * Nfeat + c;
                if (EPI == 1) v += bf2f(res[oidx]);
                if (EPI == 2) v = 0.5f * v * (1.f + erff(v * 0.70710678118654752f));
                if (EPI == 3) {
                    outf[oidx] = v + bf2f(res[oidx]);
                } else {
                    outb[oidx] = f2bf(v);
                }
            }
        }
}

// ---------------- MFMA attention: one block per (b,a), 4 waves, 8 heads ----------------
__global__ __launch_bounds__(256) void attn_mfma(
        const u16* __restrict__ qkv, const unsigned char* __restrict__ mask,
        u16* __restrict__ out) {
    __shared__ u16 sk[128][32];        // K_h row-major (b128-balanced banks)
    __shared__ u16 svt[32][136];       // V_h transposed; 272B row stride = 16B-aligned
    __shared__ u16 sp[4][32][136];     // per-wave P (q_local x key)
    __shared__ unsigned char smask[128];
    const int ba = blockIdx.x;
    const size_t rowbase = (size_t)ba * Tc;
    const int tid  = threadIdx.x;
    const int lane = tid & 63;
    const int wave = tid >> 6;
    const int wq0  = wave * 32;        // this wave's 32 query rows
    const int lrow = lane & 15, lg = lane >> 4;
    if (tid < 128) smask[tid] = mask[rowbase + tid];

    const float scale  = 0.17677669529663687f;   // 1/sqrt(32)
    const float inv128 = 1.0f / 128.0f;

    for (int h = 0; h < Hc; h++) {
        // ---- stage K (row-major) and V (transposed) ----
        {
            const int r = tid >> 1, half = tid & 1;
            const u16* gbase = qkv + (rowbase + r) * 768 + h * 32 + half * 16;
            uint4 k0 = *(const uint4*)(gbase + 256);
            uint4 k1 = *(const uint4*)(gbase + 256 + 8);
            *(uint4*)&sk[r][half * 16]     = k0;
            *(uint4*)&sk[r][half * 16 + 8] = k1;
            uint4 v0 = *(const uint4*)(gbase + 512);
            uint4 v1 = *(const uint4*)(gbase + 512 + 8);
            u16 vt[16];
            *(uint4*)&vt[0] = v0; *(uint4*)&vt[8] = v1;
            #pragma unroll
            for (int e = 0; e < 16; e++) svt[half * 16 + e][r] = vt[e];
        }
        __syncthreads();

        // ---- S = Q K^T : A=Q from global, B=K from LDS ----
        short8v a0, a1;
        {
            const u16* qp0 = qkv + (rowbase + wq0 + lrow) * 768 + h * 32 + lg * 8;
            const u16* qp1 = qp0 + 16 * 768;
            a0 = *(const short8v*)qp0;
            a1 = *(const short8v*)qp1;
        }
        float4v s_acc[2][8];
        #pragma unroll
        for (int j = 0; j < 8; j++) {
            short8v bj = *(const short8v*)&sk[j * 16 + lrow][lg * 8];
            s_acc[0][j] = __builtin_amdgcn_mfma_f32_16x16x32_bf16(a0, bj, (float4v){0.f,0.f,0.f,0.f}, 0, 0, 0);
            s_acc[1][j] = __builtin_amdgcn_mfma_f32_16x16x32_bf16(a1, bj, (float4v){0.f,0.f,0.f,0.f}, 0, 0, 0);
        }

        // ---- softmax in-register; write P to per-wave LDS ----
        #pragma unroll
        for (int i = 0; i < 2; i++) {
            #pragma unroll
            for (int r = 0; r < 4; r++) {
                float m = s_acc[i][0][r];
                #pragma unroll
                for (int j = 1; j < 8; j++) m = fmaxf(m, s_acc[i][j][r]);
                #pragma unroll
                for (int off = 1; off < 16; off <<= 1) m = fmaxf(m, __shfl_xor(m, off));
                float sum = 0.f;
                #pragma unroll
                for (int j = 0; j < 8; j++) {
                    float e = __expf((s_acc[i][j][r] - m) * scale);
                    sum += e;
                    s_acc[i][j][r] = e;
                }
                #pragma unroll
                for (int off = 1; off < 16; off <<= 1) sum += __shfl_xor(sum, off);
                const int qloc = i * 16 + lg * 4 + r;
                const bool mk = smask[wq0 + qloc] != 0;
                const float invs = 1.f / sum;
                #pragma unroll
                for (int j = 0; j < 8; j++) {
                    float pv = mk ? inv128 : s_acc[i][j][r] * invs;
                    sp[wave][qloc][j * 16 + lrow] = f2bf(pv);
                }
            }
        }

        // ---- O = P V : A=P from LDS, B=V^T from LDS ----
        float4v o_acc[2][2] = {};
        #pragma unroll
        for (int t = 0; t < 4; t++) {
            short8v pa0 = *(const short8v*)&sp[wave][lrow][t * 32 + lg * 8];
            short8v pa1 = *(const short8v*)&sp[wave][16 + lrow][t * 32 + lg * 8];
            short8v vb0 = *(const short8v*)&svt[lrow][t * 32 + lg * 8];
            short8v vb1 = *(const short8v*)&svt[16 + lrow][t * 32 + lg * 8];
            o_acc[0][0] = __builtin_amdgcn_mfma_f32_16x16x32_bf16(pa0, vb0, o_acc[0][0], 0, 0, 0);
            o_acc[0][1] = __builtin_amdgcn_mfma_f32_16x16x32_bf16(pa0, vb1, o_acc[0][1], 0, 0, 0);
            o_acc[1][0] = __builtin_amdgcn_mfma_f32_16x16x32_bf16(pa1, vb0, o_acc[1][0], 0, 0, 0);
            o_acc[1][1] = __builtin_amdgcn_mfma_f32_16x16x32_bf16(pa1, vb1, o_acc[1][1], 0, 0, 0);
        }

        // ---- write O (col = lane&15 = d, row = lg*4+reg = q) ----
        #pragma unroll
        for (int i = 0; i < 2; i++)
            #pragma unroll
            for (int n = 0; n < 2; n++)
                #pragma unroll
                for (int r = 0; r < 4; r++) {
                    size_t row = rowbase + wq0 + i * 16 + lg * 4 + r;
                    int col = h * 32 + n * 16 + lrow;
                    out[row * 256 + col] = f2bf(o_acc[i][n][r]);
                }
        __syncthreads();   // protect sk/svt before next head's staging
    }
}

extern "C" void kernel_launch(void* const* d_in, const int* in_sizes, int n_in,
                              void* d_out, int out_size, void* d_ws, size_t ws_size,
                              hipStream_t stream) {
    const float* x      = (const float*)d_in[0];
    const unsigned char* mask = (const unsigned char*)d_in[1];
    const float* ln1_w  = (const float*)d_in[2];
    const float* ln1_b  = (const float*)d_in[3];
    const float* qkv_w  = (const float*)d_in[4];
    const float* qkv_b  = (const float*)d_in[5];
    const float* proj_w = (const float*)d_in[6];
    const float* proj_b = (const float*)d_in[7];
    const float* ln2_w  = (const float*)d_in[8];
    const float* ln2_b  = (const float*)d_in[9];
    const float* fc1_w  = (const float*)d_in[10];
    const float* fc1_b  = (const float*)d_in[11];
    const float* fc2_w  = (const float*)d_in[12];
    const float* fc2_b  = (const float*)d_in[13];
    float* out = (float*)d_out;

    char* ws = (char*)d_ws;
    size_t off = 0;
    auto alloc = [&](size_t elems) -> u16* {
        u16* p = (u16*)(ws + off);
        off += ((elems * 2 + 255) / 256) * 256;
        return p;
    };
    u16* wqb  = alloc(768 * 256);
    u16* wpb  = alloc(256 * 256);
    u16* w1b  = alloc(1024 * 256);
    u16* w2b  = alloc(256 * 1024);
    u16* x1b  = alloc((size_t)NROW * Cc);
    u16* qkvb = alloc((size_t)NROW * 3 * Cc);
    u16* attb = alloc((size_t)NROW * Cc);
    u16* x2b  = alloc((size_t)NROW * Cc);
    u16* hb   = qkvb;   // fc1 output reuses qkv+attn region
    u16* x3b  = x1b;    // x3 reuses x1 region

    cast_kernel<<<(196608 + 255) / 256, 256, 0, stream>>>(qkv_w, wqb, 196608);
    cast_kernel<<<(65536  + 255) / 256, 256, 0, stream>>>(proj_w, wpb, 65536);
    cast_kernel<<<(262144 + 255) / 256, 256, 0, stream>>>(fc1_w, w1b, 262144);
    cast_kernel<<<(262144 + 255) / 256, 256, 0, stream>>>(fc2_w, w2b, 262144);
    ln_f32<<<NROW / 4, 256, 0, stream>>>(x, ln1_w, ln1_b, x1b);
    gemm_bt<256, 0><<<dim3(NROW / 64, 768 / 64), 256, 0, stream>>>(
        x1b, wqb, qkv_b, qkvb, nullptr, nullptr, 768);
    attn_mfma<<<Bc * Ac, 256, 0, stream>>>(qkvb, mask, attb);
    gemm_bt<256, 1><<<dim3(NROW / 64, 256 / 64), 256, 0, stream>>>(
        attb, wpb, proj_b, x2b, nullptr, x1b, 256);
    ln_bf16<<<NROW / 4, 256, 0, stream>>>(x2b, ln2_w, ln2_b, x3b);
    gemm_bt<256, 2><<<dim3(NROW / 64, 1024 / 64), 256, 0, stream>>>(
        x3b, w1b, fc1_b, hb, nullptr, nullptr, 1024);
    gemm_bt<1024, 3><<<dim3(NROW / 64, 256 / 64), 256, 0, stream>>>(
        hb, w2b, fc2_b, nullptr, out, x3b, 256);
}

// Round 3
// 404.861 us; speedup vs baseline: 1.7257x; 1.0728x over previous
//
#include <hip/hip_runtime.h>
#include <hip/hip_bf16.h>

typedef unsigned short u16;
typedef unsigned int   u32;

static constexpr int Bc = 8, Ac = 64, Tc = 128, Cc = 256, Hc = 8;
static constexpr int NROW = Bc * Ac * Tc;   // 65536 tokens
static constexpr int DH = Cc / Hc;          // 32

__device__ __forceinline__ float bf2f(u16 h) {
    u32 u = ((u32)h) << 16; float f; __builtin_memcpy(&f, &u, 4); return f;
}
__device__ __forceinline__ u16 f2bf(float f) {
    u32 u; __builtin_memcpy(&u, &f, 4);
    u += 0x7fffu + ((u >> 16) & 1u);   // RNE
    return (u16)(u >> 16);
}

typedef __attribute__((ext_vector_type(8))) short  short8v;
typedef __attribute__((ext_vector_type(4))) float  float4v;

__device__ __forceinline__ void gload16(const void* g, const void* lds) {
    __builtin_amdgcn_global_load_lds(
        (const __attribute__((address_space(1))) void*)g,
        (__attribute__((address_space(3))) void*)lds, 16, 0, 0);
}

// ---------------- cast all weights fp32 -> bf16, one launch ----------------
__global__ void cast4_kernel(const float* __restrict__ a, int na,
                             const float* __restrict__ b, int nb,
                             const float* __restrict__ c, int nc,
                             const float* __restrict__ d, int nd,
                             u16* oa, u16* ob, u16* oc, u16* od) {
    int i = blockIdx.x * 256 + threadIdx.x;
    if (i < na) { oa[i] = f2bf(a[i]); return; }
    i -= na;
    if (i < nb) { ob[i] = f2bf(b[i]); return; }
    i -= nb;
    if (i < nc) { oc[i] = f2bf(c[i]); return; }
    i -= nc;
    if (i < nd) { od[i] = f2bf(d[i]); }
}

// ---------------- LayerNorm, fp32 input -> bf16 out ----------------
__global__ __launch_bounds__(256) void ln_f32(const float* __restrict__ in,
        const float* __restrict__ w, const float* __restrict__ b,
        u16* __restrict__ out) {
    int row  = blockIdx.x * 4 + (threadIdx.x >> 6);
    int lane = threadIdx.x & 63;
    const float* rp = in + (size_t)row * Cc + lane * 4;
    float4 v = *(const float4*)rp;
    float s  = v.x + v.y + v.z + v.w;
    float sq = v.x * v.x + v.y * v.y + v.z * v.z + v.w * v.w;
    for (int off = 32; off; off >>= 1) { s += __shfl_xor(s, off); sq += __shfl_xor(sq, off); }
    float mean = s * (1.f / Cc);
    float rs = rsqrtf(sq * (1.f / Cc) - mean * mean + 1e-5f);
    int c0 = lane * 4;
    float vv[4] = {v.x, v.y, v.z, v.w};
    ushort4 ov;
    ov.x = f2bf((vv[0] - mean) * rs * w[c0 + 0] + b[c0 + 0]);
    ov.y = f2bf((vv[1] - mean) * rs * w[c0 + 1] + b[c0 + 1]);
    ov.z = f2bf((vv[2] - mean) * rs * w[c0 + 2] + b[c0 + 2]);
    ov.w = f2bf((vv[3] - mean) * rs * w[c0 + 3] + b[c0 + 3]);
    *(ushort4*)(out + (size_t)row * Cc + c0) = ov;
}

// ---------------- LayerNorm, bf16 input -> bf16 out ----------------
__global__ __launch_bounds__(256) void ln_bf16(const u16* __restrict__ in,
        const float* __restrict__ w, const float* __restrict__ b,
        u16* __restrict__ out) {
    int row  = blockIdx.x * 4 + (threadIdx.x >> 6);
    int lane = threadIdx.x & 63;
    const u16* rp = in + (size_t)row * Cc + lane * 4;
    ushort4 hv = *(const ushort4*)rp;
    float vv[4] = {bf2f(hv.x), bf2f(hv.y), bf2f(hv.z), bf2f(hv.w)};
    float s = vv[0] + vv[1] + vv[2] + vv[3];
    float sq = vv[0]*vv[0] + vv[1]*vv[1] + vv[2]*vv[2] + vv[3]*vv[3];
    for (int off = 32; off; off >>= 1) { s += __shfl_xor(s, off); sq += __shfl_xor(sq, off); }
    float mean = s * (1.f / Cc);
    float rs = rsqrtf(sq * (1.f / Cc) - mean * mean + 1e-5f);
    int c0 = lane * 4;
    ushort4 ov;
    ov.x = f2bf((vv[0] - mean) * rs * w[c0 + 0] + b[c0 + 0]);
    ov.y = f2bf((vv[1] - mean) * rs * w[c0 + 1] + b[c0 + 1]);
    ov.z = f2bf((vv[2] - mean) * rs * w[c0 + 2] + b[c0 + 2]);
    ov.w = f2bf((vv[3] - mean) * rs * w[c0 + 3] + b[c0 + 3]);
    *(ushort4*)(out + (size_t)row * Cc + c0) = ov;
}

// ------- GEMM 128x128 tile (m97 structure): out[M][N] = X[M][K] @ W[N][K]^T -------
// EPI: 0 bias->bf16 | 1 bias+res->bf16 | 2 bias+GELU->bf16 | 3 bias+res->fp32
template<int K, int EPI>
__global__ __launch_bounds__(256) void gemm128(
        const u16* __restrict__ X, const u16* __restrict__ W,
        const float* __restrict__ bias,
        u16* __restrict__ outb, float* __restrict__ outf,
        const u16* __restrict__ res, int Nfeat) {
    __shared__ __align__(16) u16 lA[4][128][8];   // [kchunk][row][8] fragment-order, 8 KB
    __shared__ __align__(16) u16 lB[4][128][8];
    const int bm = blockIdx.x * 128, bn = blockIdx.y * 128;
    const int tid = threadIdx.x, lane = tid & 63, wave = tid >> 6;
    const int wr = (wave >> 1) * 64, wc = (wave & 1) * 64;   // wave's 64x64 sub-tile
    const int lr = lane & 15, lg = lane >> 4;

    float4v acc[4][4] = {};
    for (int k0 = 0; k0 < K; k0 += 32) {
        // stage A,B tiles: 512 16B-chunks each; chunk c -> [kc=c>>7][row=c&127]
        #pragma unroll
        for (int q = 0; q < 2; q++) {
            const int cbase = wave * 128 + q * 64;        // wave-uniform
            const int c = cbase + lane;
            const int row = c & 127, kc = c >> 7;
            gload16(X + (size_t)(bm + row) * K + k0 + kc * 8,
                    &lA[0][0][0] + (size_t)cbase * 8);
            gload16(W + (size_t)(bn + row) * K + k0 + kc * 8,
                    &lB[0][0][0] + (size_t)cbase * 8);
        }
        __syncthreads();   // compiler drains vmcnt here (m97 structure)
        short8v a[4], b[4];
        #pragma unroll
        for (int i = 0; i < 4; i++) a[i] = *(const short8v*)&lA[lg][wr + i * 16 + lr][0];
        #pragma unroll
        for (int j = 0; j < 4; j++) b[j] = *(const short8v*)&lB[lg][wc + j * 16 + lr][0];
        #pragma unroll
        for (int i = 0; i < 4; i++)
            #pragma unroll
            for (int j = 0; j < 4; j++)
                acc[i][j] = __builtin_amdgcn_mfma_f32_16x16x32_bf16(a[i], b[j], acc[i][j], 0, 0, 0);
        __syncthreads();
    }
    // C/D layout: col = lane&15, row = (lane>>4)*4 + reg
    const int rr = lg * 4, cc0 = lr;
    #pragma unroll
    for (int i = 0; i < 4; i++)
        #pragma unroll
        for (int j = 0; j < 4; j++) {
            int c = bn + wc + j * 16 + cc0;
            float bv = bias[c];
            #pragma unroll
            for (int r4 = 0; r4 < 4; r4++) {
                int r = bm + wr + i * 16 + rr + r4;
                float v = acc[i][j][r4] + bv;
                size_t oidx = (size_t)r * Nfeat + c;
                if (EPI == 1) v += bf2f(res[oidx]);
                if (EPI == 2) v = 0.5f * v * (1.f + erff(v * 0.70710678118654752f));
                if (EPI == 3) {
                    outf[oidx] = v + bf2f(res[oidx]);
                } else {
                    outb[oidx] = f2bf(v);
                }
            }
        }
}

// ---------------- MFMA attention: one block per (b,a), 4 waves, 8 heads ----------------
__global__ __launch_bounds__(256) void attn_mfma(
        const u16* __restrict__ qkv, const unsigned char* __restrict__ mask,
        u16* __restrict__ out) {
    __shared__ u16 sk[128][32];        // K_h row-major
    __shared__ u16 svt[32][136];       // V_h transposed
    __shared__ u16 sp[4][32][136];     // per-wave P
    __shared__ unsigned char smask[128];
    const int ba = blockIdx.x;
    const size_t rowbase = (size_t)ba * Tc;
    const int tid  = threadIdx.x;
    const int lane = tid & 63;
    const int wave = tid >> 6;
    const int wq0  = wave * 32;
    const int lrow = lane & 15, lg = lane >> 4;
    if (tid < 128) smask[tid] = mask[rowbase + tid];

    const float scale  = 0.17677669529663687f;   // 1/sqrt(32)
    const float inv128 = 1.0f / 128.0f;

    for (int h = 0; h < Hc; h++) {
        {
            const int r = tid >> 1, half = tid & 1;
            const u16* gbase = qkv + (rowbase + r) * 768 + h * 32 + half * 16;
            uint4 k0 = *(const uint4*)(gbase + 256);
            uint4 k1 = *(const uint4*)(gbase + 256 + 8);
            *(uint4*)&sk[r][half * 16]     = k0;
            *(uint4*)&sk[r][half * 16 + 8] = k1;
            uint4 v0 = *(const uint4*)(gbase + 512);
            uint4 v1 = *(const uint4*)(gbase + 512 + 8);
            u16 vt[16];
            *(uint4*)&vt[0] = v0; *(uint4*)&vt[8] = v1;
            #pragma unroll
            for (int e = 0; e < 16; e++) svt[half * 16 + e][r] = vt[e];
        }
        __syncthreads();

        short8v a0, a1;
        {
            const u16* qp0 = qkv + (rowbase + wq0 + lrow) * 768 + h * 32 + lg * 8;
            const u16* qp1 = qp0 + 16 * 768;
            a0 = *(const short8v*)qp0;
            a1 = *(const short8v*)qp1;
        }
        float4v s_acc[2][8];
        #pragma unroll
        for (int j = 0; j < 8; j++) {
            short8v bj = *(const short8v*)&sk[j * 16 + lrow][lg * 8];
            s_acc[0][j] = __builtin_amdgcn_mfma_f32_16x16x32_bf16(a0, bj, (float4v){0.f,0.f,0.f,0.f}, 0, 0, 0);
            s_acc[1][j] = __builtin_amdgcn_mfma_f32_16x16x32_bf16(a1, bj, (float4v){0.f,0.f,0.f,0.f}, 0, 0, 0);
        }

        #pragma unroll
        for (int i = 0; i < 2; i++) {
            #pragma unroll
            for (int r = 0; r < 4; r++) {
                float m = s_acc[i][0][r];
                #pragma unroll
                for (int j = 1; j < 8; j++) m = fmaxf(m, s_acc[i][j][r]);
                #pragma unroll
                for (int off = 1; off < 16; off <<= 1) m = fmaxf(m, __shfl_xor(m, off));
                float sum = 0.f;
                #pragma unroll
                for (int j = 0; j < 8; j++) {
                    float e = __expf((s_acc[i][j][r] - m) * scale);
                    sum += e;
                    s_acc[i][j][r] = e;
                }
                #pragma unroll
                for (int off = 1; off < 16; off <<= 1) sum += __shfl_xor(sum, off);
                const int qloc = i * 16 + lg * 4 + r;
                const bool mk = smask[wq0 + qloc] != 0;
                const float invs = 1.f / sum;
                #pragma unroll
                for (int j = 0; j < 8; j++) {
                    float pv = mk ? inv128 : s_acc[i][j][r] * invs;
                    sp[wave][qloc][j * 16 + lrow] = f2bf(pv);
                }
            }
        }

        float4v o_acc[2][2] = {};
        #pragma unroll
        for (int t = 0; t < 4; t++) {
            short8v pa0 = *(const short8v*)&sp[wave][lrow][t * 32 + lg * 8];
            short8v pa1 = *(const short8v*)&sp[wave][16 + lrow][t * 32 + lg * 8];
            short8v vb0 = *(const short8v*)&svt[lrow][t * 32 + lg * 8];
            short8v vb1 = *(const short8v*)&svt[16 + lrow][t * 32 + lg * 8];
            o_acc[0][0] = __builtin_amdgcn_mfma_f32_16x16x32_bf16(pa0, vb0, o_acc[0][0], 0, 0, 0);
            o_acc[0][1] = __builtin_amdgcn_mfma_f32_16x16x32_bf16(pa0, vb1, o_acc[0][1], 0, 0, 0);
            o_acc[1][0] = __builtin_amdgcn_mfma_f32_16x16x32_bf16(pa1, vb0, o_acc[1][0], 0, 0, 0);
            o_acc[1][1] = __builtin_amdgcn_mfma_f32_16x16x32_bf16(pa1, vb1, o_acc[1][1], 0, 0, 0);
        }

        #pragma unroll
        for (int i = 0; i < 2; i++)
            #pragma unroll
            for (int n = 0; n < 2; n++)
                #pragma unroll
                for (int r = 0; r < 4; r++) {
                    size_t row = rowbase + wq0 + i * 16 + lg * 4 + r;
                    int col = h * 32 + n * 16 + lrow;
                    out[row * 256 + col] = f2bf(o_acc[i][n][r]);
                }
        __syncthreads();
    }
}

extern "C" void kernel_launch(void* const* d_in, const int* in_sizes, int n_in,
                              void* d_out, int out_size, void* d_ws, size_t ws_size,
                              hipStream_t stream) {
    const float* x      = (const float*)d_in[0];
    const unsigned char* mask = (const unsigned char*)d_in[1];
    const float* ln1_w  = (const float*)d_in[2];
    const float* ln1_b  = (const float*)d_in[3];
    const float* qkv_w  = (const float*)d_in[4];
    const float* qkv_b  = (const float*)d_in[5];
    const float* proj_w = (const float*)d_in[6];
    const float* proj_b = (const float*)d_in[7];
    const float* ln2_w  = (const float*)d_in[8];
    const float* ln2_b  = (const float*)d_in[9];
    const float* fc1_w  = (const float*)d_in[10];
    const float* fc1_b  = (const float*)d_in[11];
    const float* fc2_w  = (const float*)d_in[12];
    const float* fc2_b  = (const float*)d_in[13];
    float* out = (float*)d_out;

    char* ws = (char*)d_ws;
    size_t off = 0;
    auto alloc = [&](size_t elems) -> u16* {
        u16* p = (u16*)(ws + off);
        off += ((elems * 2 + 255) / 256) * 256;
        return p;
    };
    u16* wqb  = alloc(768 * 256);
    u16* wpb  = alloc(256 * 256);
    u16* w1b  = alloc(1024 * 256);
    u16* w2b  = alloc(256 * 1024);
    u16* x1b  = alloc((size_t)NROW * Cc);
    u16* qkvb = alloc((size_t)NROW * 3 * Cc);
    u16* attb = alloc((size_t)NROW * Cc);
    u16* x2b  = alloc((size_t)NROW * Cc);
    u16* hb   = qkvb;   // fc1 output reuses qkv+attn region
    u16* x3b  = x1b;    // x3 reuses x1 region

    cast4_kernel<<<(786432 + 255) / 256, 256, 0, stream>>>(
        qkv_w, 196608, proj_w, 65536, fc1_w, 262144, fc2_w, 262144,
        wqb, wpb, w1b, w2b);
    ln_f32<<<NROW / 4, 256, 0, stream>>>(x, ln1_w, ln1_b, x1b);
    gemm128<256, 0><<<dim3(NROW / 128, 768 / 128), 256, 0, stream>>>(
        x1b, wqb, qkv_b, qkvb, nullptr, nullptr, 768);
    attn_mfma<<<Bc * Ac, 256, 0, stream>>>(qkvb, mask, attb);
    gemm128<256, 1><<<dim3(NROW / 128, 256 / 128), 256, 0, stream>>>(
        attb, wpb, proj_b, x2b, nullptr, x1b, 256);
    ln_bf16<<<NROW / 4, 256, 0, stream>>>(x2b, ln2_w, ln2_b, x3b);
    gemm128<256, 2><<<dim3(NROW / 128, 1024 / 128), 256, 0, stream>>>(
        x3b, w1b, fc1_b, hb, nullptr, nullptr, 1024);
    gemm128<1024, 3><<<dim3(NROW / 128, 256 / 128), 256, 0, stream>>>(
        hb, w2b, fc2_b, nullptr, out, x3b, 256);
}